// Round 25
// baseline (123.472 us; speedup 1.0000x reference)
//
#include <hip/hip_runtime.h>

#define T_LEN 50

typedef __fp16 fp16x8 __attribute__((ext_vector_type(8)));
typedef float f32x16 __attribute__((ext_vector_type(16)));
typedef unsigned int uint4v __attribute__((ext_vector_type(4)));

__device__ __forceinline__ float EXP2(float x){ return __builtin_amdgcn_exp2f(x); }
__device__ __forceinline__ float RCP(float x){ return __builtin_amdgcn_rcpf(x); }
// pack two f32 -> two f16, ROUND-TO-NEAREST (v_cvt_f16_f32 x2 + pack).
// r24 lesson: cvt_pkrtz (RTZ) bias compounds through the 50-step recurrence;
// RTN keeps the accumulated error ~2-4x lower and insensitive to op order.
__device__ __forceinline__ unsigned PKN(float a, float b){
    const unsigned short ua = __builtin_bit_cast(unsigned short, (_Float16)a);
    const unsigned short ub = __builtin_bit_cast(unsigned short, (_Float16)b);
    return (unsigned)ua | ((unsigned)ub << 16);
}

// LSTM pointwise stage for one (layer, unit, element). Gates pre-scaled:
// i,f,o by S1=-log2e; g by S2=-2log2e (folded into weights+bias).
__device__ __forceinline__ void act(float gi, float gf, float gg, float go,
                                    float& c, float& h){
    const float S2 = -2.8853900817779268f;
    const float p = EXP2(gi);
    const float r = EXP2(gf);
    const float q = EXP2(gg);
    const float s = EXP2(go);
    const float A  = 1.0f + r;
    const float BC = (1.0f + p) * (1.0f + q);
    const float num = fmaf(c, BC, (1.0f - q) * A);
    c = num * RCP(A * BC);
    const float u = EXP2(fminf(c * S2, 96.0f));
    h = (1.0f - u) * RCP((1.0f + s) * (1.0f + u));
}

// per-tile recurrence state (named scalars — no runtime-indexed arrays)
struct TS {
    float c0l, c0h, c1l, c1h, acc;
    unsigned p0, p1, p2, p3;   // pk_h0_01, pk_h0_23, pk_h1_01, pk_h1_23
};

// INTRA-WAVE ILP-2: each wave owns 64 elements as TWO independent 32-element
// tiles, interleaved per time step (2 MFMAs + 8 acts) — while tile A's serial
// act-chain computes, tile B's work issues from the same wave.
// Per tile: one mfma_f32_32x32x16_f16 per step: L0 gates(t) rows 0-15,
// L1 gates(t-1) rows 16-31. B = [x(t) k0-1 | h0 k2-5 | h1 k6-9]. Bias in C.
// x: full 50-step one-shot f16 LDS stage (no mid-kernel reload -> no spill).
__global__ __launch_bounds__(128, 3) void lstm_mfma32(
    const float* __restrict__ x,
    const float* __restrict__ Wih0, const float* __restrict__ Whh0,
    const float* __restrict__ bih0, const float* __restrict__ bhh0,
    const float* __restrict__ Wih1, const float* __restrict__ Whh1,
    const float* __restrict__ bih1, const float* __restrict__ bhh1,
    const float* __restrict__ Wout, const float* __restrict__ bout,
    float* __restrict__ out, int B)
{
    __shared__ float2 wout_s[T_LEN*2];        // [t][h]=(W[t*4+h],W[t*4+h+2])
    __shared__ unsigned xstage[2*64*T_LEN];   // packed f16 x, per-wave regions
    const int tid = threadIdx.x;
    if (tid < T_LEN*2){
        const int t = tid >> 1, hh = tid & 1;
        wout_s[tid] = make_float2(Wout[t*4+hh], Wout[t*4+hh+2]);
    }
    __syncthreads();

    const int lane = tid & 63;
    const int e = lane & 31;          // element column within tile
    const int h = lane >> 5;          // half: owns units {h, 2+h} per layer
    const int wslot = tid >> 6;
    const int wave = (blockIdx.x*128 + tid) >> 6;
    const int E0 = wave * 64;         // this wave's 64 elements (2 tiles)
    if (E0 >= B) return;

    unsigned* xr = xstage + wslot * (64*T_LEN);

    const float S1 = -1.4426950408889634f;
    const float S2 = -2.8853900817779268f;

    // ---- A fragment: lane supplies row mA=e, k=8h+0..7 (shared by tiles) ----
    const int qA = e >> 2, tA = e & 3;
    const float sA = (tA == 2) ? S2 : S1;
    uint4v au;
#pragma unroll
    for (int p = 0; p < 4; ++p){
        float vv[2];
#pragma unroll
        for (int z = 0; z < 2; ++z){
            const int k = 8*h + 2*p + z;
            float v = 0.f;
            if (qA < 4){                          // L0 rows: x(k0-1), h0(k2-5)
                const int r = tA*4 + qA;
                if (k < 2)      v = Wih0[r*2 + k];
                else if (k < 6) v = Whh0[r*4 + (k-2)];
            } else {                              // L1 rows: h0(k2-5), h1(k6-9)
                const int r = tA*4 + (qA-4);
                if (k >= 2 && k < 6)       v = Wih1[r*4 + (k-2)];
                else if (k >= 6 && k < 10) v = Whh1[r*4 + (k-6)];
            }
            vv[z] = v * sA;
        }
        au[p] = PKN(vv[0], vv[1]);
    }
    const fp16x8 Afrag = __builtin_bit_cast(fp16x8, au);

    // ---- bias as C operand (loop-invariant, shared by tiles) ----
    f32x16 biasC;
#pragma unroll
    for (int r = 0; r < 16; ++r){
        const int m = (r&3) + 8*(r>>2) + 4*h;
        const int q = m >> 2, tg = m & 3;
        const float st = (tg == 2) ? S2 : S1;
        if (q < 4){ const int rr = tg*4 + q;      biasC[r] = (bih0[rr]+bhh0[rr])*st; }
        else      { const int rr = tg*4 + (q-4);  biasC[r] = (bih1[rr]+bhh1[rr])*st; }
    }

    const float* xg = x + (size_t)E0 * (T_LEN*2);

    // ---- stage 64 elems x 50 steps: 3200 u32 = 50/lane (transient regs;
    //      one-shot before any loop state is live -> no spill) ----
#pragma unroll 10
    for (int k = 0; k < 50; ++k){
        const int i = 64*k + lane;
        const int e_ = i / T_LEN, t_ = i % T_LEN;
        const float2 v = *reinterpret_cast<const float2*>(xg + e_*100 + t_*2);
        xr[e_*T_LEN + t_] = PKN(v.x, v.y);
    }

    TS sA_, sB_;
    sA_.c0l=0.f; sA_.c0h=0.f; sA_.c1l=0.f; sA_.c1h=0.f; sA_.acc=0.f;
    sA_.p0=0u; sA_.p1=0u; sA_.p2=0u; sA_.p3=0u;
    sB_ = sA_;

    const unsigned* xrA = xr + e*T_LEN;          // tile A: elements E0+e
    const unsigned* xrB = xr + (32+e)*T_LEN;     // tile B: elements E0+32+e

    auto mstep = [&](TS& st, unsigned ux, float2 wo){
        uint4v bu;
        bu[0] = h ? st.p3 : ux;
        bu[1] = st.p0;
        bu[2] = st.p1;
        bu[3] = st.p2;
        const f32x16 d = __builtin_amdgcn_mfma_f32_32x32x16_f16(
            Afrag, __builtin_bit_cast(fp16x8, bu), biasC, 0, 0, 0);
        float h0l,h0h,h1l,h1h;
        act(d[0], d[1], d[2], d[3],   st.c0l, h0l);
        act(d[4], d[5], d[6], d[7],   st.c0h, h0h);
        act(d[8], d[9], d[10],d[11],  st.c1l, h1l);
        act(d[12],d[13],d[14],d[15],  st.c1h, h1h);
        st.acc = fmaf(h1l, wo.x, fmaf(h1h, wo.y, st.acc));
        const float r0l = __shfl_xor(h0l,32,64), r0h = __shfl_xor(h0h,32,64);
        const float r1l = __shfl_xor(h1l,32,64), r1h = __shfl_xor(h1h,32,64);
        st.p0 = PKN(h0l, r0l);
        st.p1 = PKN(h0h, r0h);
        st.p2 = PKN(h1l, r1l);
        st.p3 = PKN(r1h, h1h);
    };

    auto prol = [&](TS& st, unsigned ux){
        uint4v bu; bu[0] = h ? 0u : ux; bu[1]=0u; bu[2]=0u; bu[3]=0u;
        const f32x16 d = __builtin_amdgcn_mfma_f32_32x32x16_f16(
            Afrag, __builtin_bit_cast(fp16x8, bu), biasC, 0, 0, 0);
        float h0l, h0h;
        act(d[0],d[1],d[2],d[3], st.c0l, h0l);
        act(d[4],d[5],d[6],d[7], st.c0h, h0h);
        const float r0l = __shfl_xor(h0l, 32, 64);
        const float r0h = __shfl_xor(h0h, 32, 64);
        st.p0 = PKN(h0l, r0l);
        st.p1 = PKN(h0h, r0h);
    };

    // ---- prologue t=0: L0 only, both tiles ----
    prol(sA_, xrA[0]);
    prol(sB_, xrB[0]);

    // ---- main loop: two independent chains interleaved per step ----
    for (int t = 1; t < T_LEN; ++t){
        const unsigned xa = xrA[t];
        const unsigned xb = xrB[t];
        const float2 wo = wout_s[(t-1)*2 + h];
        mstep(sA_, xa, wo);
        mstep(sB_, xb, wo);
    }

    // ---- epilogue: L1 at t=49, both tiles ----
    auto epil = [&](TS& st, float2 wo) -> float {
        uint4v bu;
        bu[0] = h ? st.p3 : 0u;
        bu[1] = st.p0; bu[2] = st.p1; bu[3] = st.p2;
        const f32x16 d = __builtin_amdgcn_mfma_f32_32x32x16_f16(
            Afrag, __builtin_bit_cast(fp16x8, bu), biasC, 0, 0, 0);
        float h1l, h1h;
        act(d[8], d[9], d[10],d[11],  st.c1l, h1l);
        act(d[12],d[13],d[14],d[15],  st.c1h, h1h);
        return fmaf(h1l, wo.x, fmaf(h1h, wo.y, st.acc));
    };
    const float2 wo49 = wout_s[49*2 + h];
    float aA = epil(sA_, wo49);
    float aB = epil(sB_, wo49);

    aA += __shfl_xor(aA, 32, 64);
    aB += __shfl_xor(aB, 32, 64);
    if (h == 0){
        out[E0 + e]      = RCP(1.0f + EXP2((aA + bout[0]) * S1));
        out[E0 + 32 + e] = RCP(1.0f + EXP2((aB + bout[0]) * S1));
    }
}

extern "C" void kernel_launch(void* const* d_in, const int* in_sizes, int n_in,
                              void* d_out, int out_size, void* d_ws, size_t ws_size,
                              hipStream_t stream)
{
    const float* x    = (const float*)d_in[0];
    const float* Wih0 = (const float*)d_in[1];
    const float* Whh0 = (const float*)d_in[2];
    const float* bih0 = (const float*)d_in[3];
    const float* bhh0 = (const float*)d_in[4];
    const float* Wih1 = (const float*)d_in[5];
    const float* Whh1 = (const float*)d_in[6];
    const float* bih1 = (const float*)d_in[7];
    const float* bhh1 = (const float*)d_in[8];
    const float* Wout = (const float*)d_in[9];
    const float* bout = (const float*)d_in[10];
    float* out = (float*)d_out;

    const int B = in_sizes[0] / (T_LEN*2);
    const int waves = (B + 63) / 64;          // each wave = 64 elements (2 tiles)
    const int blocks = (waves + 1) / 2;       // 2 waves (128 threads) per block
    lstm_mfma32<<<blocks, 128, 0, stream>>>(x, Wih0, Whh0, bih0, bhh0,
                                            Wih1, Whh1, bih1, bhh1,
                                            Wout, bout, out, B);
}

// Round 26
// 92.431 us; speedup vs baseline: 1.3358x; 1.3358x over previous
//
#include <hip/hip_runtime.h>

#define T_LEN 50

typedef __fp16 fp16x8 __attribute__((ext_vector_type(8)));
typedef float f32x16 __attribute__((ext_vector_type(16)));
typedef unsigned int uint4v __attribute__((ext_vector_type(4)));

__device__ __forceinline__ float EXP2(float x){ return __builtin_amdgcn_exp2f(x); }
__device__ __forceinline__ float RCP(float x){ return __builtin_amdgcn_rcpf(x); }
__device__ __forceinline__ unsigned PKU(float a, float b){
    return __builtin_bit_cast(unsigned, __builtin_amdgcn_cvt_pkrtz(a, b));
}

// LSTM pointwise stage for one (layer, unit, element). Gates pre-scaled:
// i,f,o by S1=-log2e; g by S2=-2log2e (folded into weights+bias).
__device__ __forceinline__ void act(float gi, float gf, float gg, float go,
                                    float& c, float& h){
    const float S2 = -2.8853900817779268f;
    const float p = EXP2(gi);
    const float r = EXP2(gf);
    const float q = EXP2(gg);
    const float s = EXP2(go);
    const float A  = 1.0f + r;
    const float BC = (1.0f + p) * (1.0f + q);
    const float num = fmaf(c, BC, (1.0f - q) * A);
    c = num * RCP(A * BC);
    const float u = EXP2(fminf(c * S2, 96.0f));
    h = (1.0f - u) * RCP((1.0f + s) * (1.0f + u));
}

// Wave tile: 32 elements. One mfma_f32_32x32x16_f16 per step: L0 gates(t) rows 0-15,
// L1 gates(t-1) rows 16-31. B = [x(t) k0-1 | h0 k2-5 | h1 k6-9 | 0]. Bias in C.
// x staged once, fully (50 steps), as packed-f16 u32 in wave-private LDS:
// no register-resident chunk -> no scratch spill. This configuration (r18) is
// the empirical optimum of 8 structure/residency variants (r18-r25); it sits
// within ~7% of the transcendental-issue floor (28 trans/wave-step x ~12.6cyc
// + ~65 regular VALU x 2cyc, at ~6 resident waves/SIMD).
// Stride-50 dword access: 18e mod 32 -> 2-way bank alias = free.
__global__ __launch_bounds__(256, 6) void lstm_mfma32(
    const float* __restrict__ x,
    const float* __restrict__ Wih0, const float* __restrict__ Whh0,
    const float* __restrict__ bih0, const float* __restrict__ bhh0,
    const float* __restrict__ Wih1, const float* __restrict__ Whh1,
    const float* __restrict__ bih1, const float* __restrict__ bhh1,
    const float* __restrict__ Wout, const float* __restrict__ bout,
    float* __restrict__ out, int B)
{
    __shared__ float2 wout_s[T_LEN*2];            // [t][h]=(W[t*4+h],W[t*4+h+2])
    __shared__ unsigned xstage[4*32*T_LEN];       // packed f16 x, per-wave regions
    const int tid = threadIdx.x;
    if (tid < T_LEN*2){
        const int t = tid >> 1, hh = tid & 1;
        wout_s[tid] = make_float2(Wout[t*4+hh], Wout[t*4+hh+2]);
    }
    __syncthreads();

    const int lane = tid & 63;
    const int e = lane & 31;          // element column
    const int h = lane >> 5;          // half: owns units {h, 2+h} per layer
    const int wslot = tid >> 6;
    const int wave = (blockIdx.x*256 + tid) >> 6;
    const int E0 = wave * 32;
    if (E0 >= B) return;

    unsigned* xr = xstage + wslot * (32*T_LEN);

    const float S1 = -1.4426950408889634f;
    const float S2 = -2.8853900817779268f;

    // ---- A fragment: lane supplies row mA=e, k=8h+0..7 ----
    const int qA = e >> 2, tA = e & 3;
    const float sA = (tA == 2) ? S2 : S1;
    uint4v au;
#pragma unroll
    for (int p = 0; p < 4; ++p){
        float vv[2];
#pragma unroll
        for (int z = 0; z < 2; ++z){
            const int k = 8*h + 2*p + z;
            float v = 0.f;
            if (qA < 4){                          // L0 rows: x(k0-1), h0(k2-5)
                const int r = tA*4 + qA;
                if (k < 2)      v = Wih0[r*2 + k];
                else if (k < 6) v = Whh0[r*4 + (k-2)];
            } else {                              // L1 rows: h0(k2-5), h1(k6-9)
                const int r = tA*4 + (qA-4);
                if (k >= 2 && k < 6)       v = Wih1[r*4 + (k-2)];
                else if (k >= 6 && k < 10) v = Whh1[r*4 + (k-6)];
            }
            vv[z] = v * sA;
        }
        au[p] = PKU(vv[0], vv[1]);
    }
    const fp16x8 Afrag = __builtin_bit_cast(fp16x8, au);

    // ---- bias as C operand (loop-invariant) ----
    f32x16 biasC;
#pragma unroll
    for (int r = 0; r < 16; ++r){
        const int m = (r&3) + 8*(r>>2) + 4*h;
        const int q = m >> 2, tg = m & 3;
        const float st = (tg == 2) ? S2 : S1;
        if (q < 4){ const int rr = tg*4 + q;      biasC[r] = (bih0[rr]+bhh0[rr])*st; }
        else      { const int rr = tg*4 + (q-4);  biasC[r] = (bih1[rr]+bhh1[rr])*st; }
    }

    const float* xg = x + (size_t)E0 * (T_LEN*2);

    // ---- stage all 50 steps: 1600 u32 = 25 per lane, coalesced float2 loads ----
#pragma unroll
    for (int k = 0; k < 25; ++k){
        const int i = 64*k + lane;
        const int e_ = i / T_LEN, t_ = i % T_LEN;
        const float2 v = *reinterpret_cast<const float2*>(xg + e_*100 + t_*2);
        xr[e_*T_LEN + t_] = PKU(v.x, v.y);
    }

    float c0l=0.f, c0h=0.f, c1l=0.f, c1h=0.f, acc=0.f;
    unsigned pk_h0_01=0u, pk_h0_23=0u, pk_h1_01=0u, pk_h1_23=0u;

    auto mainstep = [&](int t, unsigned ux){
        uint4v bu;
        bu[0] = h ? pk_h1_23 : ux;
        bu[1] = pk_h0_01;
        bu[2] = pk_h0_23;
        bu[3] = pk_h1_01;
        const f32x16 d = __builtin_amdgcn_mfma_f32_32x32x16_f16(
            Afrag, __builtin_bit_cast(fp16x8, bu), biasC, 0, 0, 0);
        float h0l,h0h,h1l,h1h;
        act(d[0], d[1], d[2], d[3],  c0l, h0l);
        act(d[4], d[5], d[6], d[7],  c0h, h0h);
        act(d[8], d[9], d[10],d[11], c1l, h1l);
        act(d[12],d[13],d[14],d[15], c1h, h1h);
        const float2 wo = wout_s[(t-1)*2 + h];
        acc = fmaf(h1l, wo.x, fmaf(h1h, wo.y, acc));
        const float r0l = __shfl_xor(h0l,32,64), r0h = __shfl_xor(h0h,32,64);
        const float r1l = __shfl_xor(h1l,32,64), r1h = __shfl_xor(h1h,32,64);
        pk_h0_01 = PKU(h0l, r0l);
        pk_h0_23 = PKU(h0h, r0h);
        pk_h1_01 = PKU(h1l, r1l);
        pk_h1_23 = PKU(r1h, h1h);
    };

    // ---- prologue t=0: L0 only ----
    {
        const unsigned ux = xr[e*T_LEN + 0];
        uint4v bu; bu[0] = h ? 0u : ux; bu[1]=0u; bu[2]=0u; bu[3]=0u;
        const f32x16 d = __builtin_amdgcn_mfma_f32_32x32x16_f16(
            Afrag, __builtin_bit_cast(fp16x8, bu), biasC, 0, 0, 0);
        float h0l, h0h;
        act(d[0],d[1],d[2],d[3], c0l, h0l);
        act(d[4],d[5],d[6],d[7], c0h, h0h);
        const float r0l = __shfl_xor(h0l, 32, 64);
        const float r0h = __shfl_xor(h0h, 32, 64);
        pk_h0_01 = PKU(h0l, r0l);
        pk_h0_23 = PKU(h0h, r0h);
    }

    for (int t = 1; t < T_LEN; ++t)
        mainstep(t, xr[e*T_LEN + t]);

    // ---- epilogue: L1 at t=49 ----
    {
        uint4v bu;
        bu[0] = h ? pk_h1_23 : 0u;
        bu[1] = pk_h0_01; bu[2] = pk_h0_23; bu[3] = pk_h1_01;
        const f32x16 d = __builtin_amdgcn_mfma_f32_32x32x16_f16(
            Afrag, __builtin_bit_cast(fp16x8, bu), biasC, 0, 0, 0);
        float h1l, h1h;
        act(d[8], d[9], d[10],d[11], c1l, h1l);
        act(d[12],d[13],d[14],d[15], c1h, h1h);
        const float2 wo = wout_s[49*2 + h];
        acc = fmaf(h1l, wo.x, fmaf(h1h, wo.y, acc));
    }

    acc += __shfl_xor(acc, 32, 64);
    if (h == 0){
        const float z = acc + bout[0];
        out[E0 + e] = RCP(1.0f + EXP2(z * S1));   // sigmoid
    }
}

extern "C" void kernel_launch(void* const* d_in, const int* in_sizes, int n_in,
                              void* d_out, int out_size, void* d_ws, size_t ws_size,
                              hipStream_t stream)
{
    const float* x    = (const float*)d_in[0];
    const float* Wih0 = (const float*)d_in[1];
    const float* Whh0 = (const float*)d_in[2];
    const float* bih0 = (const float*)d_in[3];
    const float* bhh0 = (const float*)d_in[4];
    const float* Wih1 = (const float*)d_in[5];
    const float* Whh1 = (const float*)d_in[6];
    const float* bih1 = (const float*)d_in[7];
    const float* bhh1 = (const float*)d_in[8];
    const float* Wout = (const float*)d_in[9];
    const float* bout = (const float*)d_in[10];
    float* out = (float*)d_out;

    const int B = in_sizes[0] / (T_LEN*2);
    const int waves = (B + 31) / 32;
    const int blocks = (waves + 3) / 4;       // 4 waves per 256-thread block
    lstm_mfma32<<<blocks, 256, 0, stream>>>(x, Wih0, Whh0, bih0, bhh0,
                                            Wih1, Whh1, bih1, bhh1,
                                            Wout, bout, out, B);
}